// Round 3
// baseline (794.964 us; speedup 1.0000x reference)
//
#include <hip/hip_runtime.h>

// INT4PackedLinear: y[64,28672] = x[64,8192] @ dequant(w_packed, scales) + bias
//
// HARNESS DTYPE CONTRACT (established rounds 0-2): float16 tensors are
// promoted to FLOAT32 (harness dtype set is {bf16, f32, int}; round-1
// absmax 2.68e36 == fp16-inf in high half of an f32 word; round-2 all-bf16
// kernel — index-audited correct — still failed => inputs are not bf16).
//   x: f32 [64,8192], w_packed: int32 [4096,28672], scales: f32 [64,28672],
//   bias: f32 [28672], y: f32 [64,28672].
//
// Strategy: register-direct dequant GEMM, no LDS.
//  - Pre-kernel converts x f32->bf16 (RNE) into d_ws (1 MB, L2-resident).
//  - mfma_f32_16x16x32_bf16; B-fragment (n = lane&15, k = quad*8+j) fed
//    directly by per-lane global dword loads of w_packed[kk][n]; each load
//    instr covers 4 full 64B lines -> full HBM line use on the 470 MB stream.
//  - Register double-buffer: prefetch next 128-k group's 16 w-dwords during
//    compute (4 KB/wave in flight vs 9.2 KB/CU Little's-law need at 7 waves/CU).
//  - Dequant: f32 (nib-8)*scale, RNE-packed to bf16 pairs (error << 0.595 thr).
//  - block=64 (1 wave, BN=16), grid=1792 -> exactly 7 waves/CU, zero imbalance.

typedef short  short8  __attribute__((ext_vector_type(8)));
typedef float  float4v __attribute__((ext_vector_type(4)));

constexpr int Kd = 8192;
constexpr int Nd = 28672;

// round-to-nearest-even f32 -> bf16 bits (low 16 of result)
__device__ __forceinline__ unsigned f32_to_bf16_rn(float f) {
    unsigned u = __builtin_bit_cast(unsigned, f);
    return (u + 0x7FFFu + ((u >> 16) & 1u)) >> 16;
}

// ---------------- pre-kernel: x f32 -> bf16 into workspace ----------------
__global__ __launch_bounds__(256)
void cvt_x_kernel(const float* __restrict__ x, unsigned short* __restrict__ o) {
    const int i = (blockIdx.x * 256 + threadIdx.x) * 8;
    float4v a = *(const float4v*)(x + i);
    float4v b = *(const float4v*)(x + i + 4);
    union { unsigned short s[8]; short8 v; } r;
    #pragma unroll
    for (int j = 0; j < 4; ++j) {
        r.s[j]     = (unsigned short)f32_to_bf16_rn(a[j]);
        r.s[4 + j] = (unsigned short)f32_to_bf16_rn(b[j]);
    }
    *(short8*)(o + i) = r.v;
}

// ---------------- main kernel ----------------
__device__ __forceinline__ void loadw(int v[16], const int* __restrict__ p) {
    #pragma unroll
    for (int it = 0; it < 4; ++it)
        #pragma unroll
        for (int i = 0; i < 4; ++i)
            v[it * 4 + i] = p[(long)(it * 16 + i) * Nd];
}

template <bool PRE>
__device__ __forceinline__ short8 load_a(const unsigned short* xb, const float* xf) {
    if constexpr (PRE) {
        return *(const short8*)xb;
    } else {
        float4v a = *(const float4v*)xf;
        float4v b = *(const float4v*)(xf + 4);
        union { unsigned short s[8]; short8 v; } r;
        #pragma unroll
        for (int j = 0; j < 4; ++j) {
            r.s[j]     = (unsigned short)f32_to_bf16_rn(a[j]);
            r.s[4 + j] = (unsigned short)f32_to_bf16_rn(b[j]);
        }
        return r.v;
    }
}

template <bool PRE>
__device__ __forceinline__ void compute_group(
        const int v[16], float s,
        const unsigned short* __restrict__ xg, const float* __restrict__ xgf,
        float4v& acc0, float4v& acc1, float4v& acc2, float4v& acc3)
{
    #pragma unroll
    for (int it = 0; it < 4; ++it) {
        union { short8 h; unsigned u[4]; } bu;
        #pragma unroll
        for (int i = 0; i < 4; ++i) {
            int w = v[it * 4 + i];
            float wl = (float)((w & 15) - 8) * s;
            float wh = (float)(((w >> 4) & 15) - 8) * s;
            bu.u[i] = f32_to_bf16_rn(wl) | (f32_to_bf16_rn(wh) << 16); // (even k, odd k)
        }
        const short8 b = bu.h;

        short8 a0 = load_a<PRE>(xg + it * 32,             xgf + it * 32);
        short8 a1 = load_a<PRE>(xg + it * 32 + 16L * Kd,  xgf + it * 32 + 16L * Kd);
        short8 a2 = load_a<PRE>(xg + it * 32 + 32L * Kd,  xgf + it * 32 + 32L * Kd);
        short8 a3 = load_a<PRE>(xg + it * 32 + 48L * Kd,  xgf + it * 32 + 48L * Kd);

        acc0 = __builtin_amdgcn_mfma_f32_16x16x32_bf16(a0, b, acc0, 0, 0, 0);
        acc1 = __builtin_amdgcn_mfma_f32_16x16x32_bf16(a1, b, acc1, 0, 0, 0);
        acc2 = __builtin_amdgcn_mfma_f32_16x16x32_bf16(a2, b, acc2, 0, 0, 0);
        acc3 = __builtin_amdgcn_mfma_f32_16x16x32_bf16(a3, b, acc3, 0, 0, 0);
    }
}

template <bool PRE>
__global__ __launch_bounds__(64)
void int4_linear_kernel(const unsigned short* __restrict__ xb,  // bf16 ws (PRE)
                        const float*          __restrict__ xf,  // f32 x  (!PRE)
                        const int*            __restrict__ wp,
                        const float*          __restrict__ scales,
                        const float*          __restrict__ bias,
                        float*                __restrict__ y)
{
    const int lane = threadIdx.x;        // block = 64 = 1 wave
    const int q    = lane >> 4;          // quad: k offset q*8, out-row base q*4
    const int c    = lane & 15;          // n within tile / m within A-tile
    const int n    = blockIdx.x * 16 + c;

    const int* wpg = wp + (long)(q * 4) * Nd + n;   // + (it*16+i)*Nd + g*64*Nd
    const unsigned short* xrow  = xb + (long)c * Kd + q * 8;
    const float*          xrowf = xf + (long)c * Kd + q * 8;
    const float* s_l = scales + n;

    float4v acc0 = {0.f, 0.f, 0.f, 0.f};
    float4v acc1 = {0.f, 0.f, 0.f, 0.f};
    float4v acc2 = {0.f, 0.f, 0.f, 0.f};
    float4v acc3 = {0.f, 0.f, 0.f, 0.f};

    int vA[16], vB[16];
    loadw(vA, wpg);                       // group 0 in flight

    for (int g = 0; g < 64; g += 2) {
        loadw(vB, wpg + 64L * Nd);        // prefetch group g+1
        compute_group<PRE>(vA, s_l[(long)g * Nd],
                           xrow + (long)g * 128, xrowf + (long)g * 128,
                           acc0, acc1, acc2, acc3);

        if (g < 62)
            loadw(vA, wpg + 128L * Nd);   // prefetch group g+2
        compute_group<PRE>(vB, s_l[(long)(g + 1) * Nd],
                           xrow + (long)(g + 1) * 128, xrowf + (long)(g + 1) * 128,
                           acc0, acc1, acc2, acc3);

        wpg += 128L * Nd;
    }

    // Epilogue: C/D row m = 16*mt + q*4 + r, col n. f32 acc + f32 bias -> f32.
    const float bn = bias[n];
    const int rb = q * 4;
    #pragma unroll
    for (int r = 0; r < 4; ++r) {
        y[(long)( 0 + rb + r) * Nd + n] = acc0[r] + bn;
        y[(long)(16 + rb + r) * Nd + n] = acc1[r] + bn;
        y[(long)(32 + rb + r) * Nd + n] = acc2[r] + bn;
        y[(long)(48 + rb + r) * Nd + n] = acc3[r] + bn;
    }
}

extern "C" void kernel_launch(void* const* d_in, const int* in_sizes, int n_in,
                              void* d_out, int out_size, void* d_ws, size_t ws_size,
                              hipStream_t stream) {
    const float* x      = (const float*)d_in[0];
    const int*   wp     = (const int*)d_in[1];
    const float* scales = (const float*)d_in[2];
    const float* bias   = (const float*)d_in[3];
    float*       y      = (float*)d_out;

    const size_t xb_bytes = (size_t)64 * Kd * sizeof(unsigned short); // 1 MB
    dim3 grid(Nd / 16);   // 1792 blocks -> exactly 7 waves/CU
    dim3 block(64);

    if (ws_size >= xb_bytes) {
        unsigned short* xb = (unsigned short*)d_ws;
        cvt_x_kernel<<<dim3(256), dim3(256), 0, stream>>>(x, xb);  // 64*8192/8/256
        int4_linear_kernel<true><<<grid, block, 0, stream>>>(xb, x, wp, scales, bias, y);
    } else {
        int4_linear_kernel<false><<<grid, block, 0, stream>>>(nullptr, x, wp, scales, bias, y);
    }
}

// Round 4
// 767.774 us; speedup vs baseline: 1.0354x; 1.0354x over previous
//
#include <hip/hip_runtime.h>

// INT4PackedLinear: y[64,28672] = x[64,8192] @ dequant(w_packed, scales) + bias
// Dtype contract (verified R0-R3): x/scales/bias/y are FLOAT32, w_packed int32.
//
// R3 post-mortem: register-direct w loads (1 dword/lane, 256B/instr) + compiler
// sinking the prefetch => latency-bound, 1.44 TB/s, 333 us. Fix: barrier-phased
// bulk staging through LDS with dwordx4 gathers (1KB/instr), dequant-on-write,
// K-split=4 for 28 waves/CU, f32 atomic epilogue into bias-initialized y.

typedef short  short8  __attribute__((ext_vector_type(8)));
typedef float  float4v __attribute__((ext_vector_type(4)));
typedef int    int4v   __attribute__((ext_vector_type(4)));
typedef unsigned int uint4v __attribute__((ext_vector_type(4)));

constexpr int Kd = 8192;
constexpr int Nd = 28672;
constexpr int KSPLIT = 4;           // 4 k-partitions of 2048
constexpr int GPS = 16;             // 128-k groups per partition
constexpr int LDS_STRIDE = 68;      // dwords/row: %4==0 (b128 align), %32==4 (2-way reads)

__device__ __forceinline__ unsigned f32_to_bf16_rn(float f) {
    unsigned u = __builtin_bit_cast(unsigned, f);
    return (u + 0x7FFFu + ((u >> 16) & 1u)) >> 16;
}

// ---- y := bias (broadcast over 64 rows); 1792 blocks x 256 thr x float4 ----
__global__ __launch_bounds__(256)
void init_y_kernel(const float* __restrict__ bias, float* __restrict__ y) {
    const int gid = blockIdx.x * 256 + threadIdx.x;       // 458752 = 64*7168
    const int m  = gid / (Nd / 4);
    const int nq = gid % (Nd / 4);
    ((float4v*)y)[(long)m * (Nd / 4) + nq] = ((const float4v*)bias)[nq];
}

// ---- x f32 -> bf16 into workspace; 256 blocks ----
__global__ __launch_bounds__(256)
void cvt_x_kernel(const float* __restrict__ x, unsigned short* __restrict__ o) {
    const int i = (blockIdx.x * 256 + threadIdx.x) * 8;
    float4v a = *(const float4v*)(x + i);
    float4v b = *(const float4v*)(x + i + 4);
    union { unsigned short s[8]; short8 v; } r;
    #pragma unroll
    for (int j = 0; j < 4; ++j) {
        r.s[j]     = (unsigned short)f32_to_bf16_rn(a[j]);
        r.s[4 + j] = (unsigned short)f32_to_bf16_rn(b[j]);
    }
    *(short8*)(o + i) = r.v;
}

// ---- main: grid (448, 4), block 256 ----
__global__ __launch_bounds__(256, 6)
void int4_main_kernel(const unsigned short* __restrict__ xb,
                      const int*            __restrict__ wp,
                      const float*          __restrict__ scales,
                      float*                __restrict__ y)
{
    __shared__ unsigned lds_w[64 * LDS_STRIDE];   // 17,408 B: bf16-pair dwords

    const int t    = threadIdx.x;
    const int lane = t & 63;
    const int wv   = t >> 6;            // wave 0..3 -> n-tile
    const int q    = lane >> 4;         // quad
    const int c    = lane & 15;
    const int n0   = blockIdx.x * 64;
    const int kz   = blockIdx.y;        // k-split 0..3

    // staging role: row-in-band sr (0..15), 16B segment ss (0..15)
    const int sr = t >> 4, ss = t & 15;
    // packed rows for this partition: [kz*1024, kz*1024+1024)
    const int*   wp_b = wp + (long)(kz * 1024 + sr) * Nd + n0 + 4 * ss;
    const float* sc_b = scales + (long)(kz * GPS) * Nd + n0 + 4 * ss;

    // A: bf16 x from ws. k-base for this partition = kz*2048.
    const unsigned short* xb_b = xb + (long)c * Kd + kz * 2048 + q * 8;

    float4v acc[4] = {};   // 4 m-tiles x 4 f32

    for (int g = 0; g < GPS; ++g) {
        // ---- stage one 128-k group (64 packed rows x 64 n) ----
        const float4v s4 = *(const float4v*)(sc_b + (long)g * Nd);
        const int* wg = wp_b + (long)g * 64 * Nd;
        #pragma unroll
        for (int i = 0; i < 4; ++i) {
            int4v v = *(const int4v*)(wg + (long)i * 16 * Nd);  // 1KB/wave-instr
            uint4v pk;
            #pragma unroll
            for (int j = 0; j < 4; ++j) {
                float lo = (float)((v[j] & 15) - 8) * s4[j];
                float hi = (float)(((v[j] >> 4) & 15) - 8) * s4[j];
                pk[j] = f32_to_bf16_rn(lo) | (f32_to_bf16_rn(hi) << 16);
            }
            *(uint4v*)&lds_w[(i * 16 + sr) * LDS_STRIDE + 4 * ss] = pk;
        }
        __syncthreads();

        // ---- compute: 4 k-steps of 32 ----
        const unsigned short* xg = xb_b + g * 128;
        #pragma unroll
        for (int it = 0; it < 4; ++it) {
            union { short8 h; unsigned u[4]; } bu;
            #pragma unroll
            for (int i = 0; i < 4; ++i)
                bu.u[i] = lds_w[(it * 16 + q * 4 + i) * LDS_STRIDE + wv * 16 + c];
            const short8 b = bu.h;

            const unsigned short* xk = xg + it * 32;
            #pragma unroll
            for (int mt = 0; mt < 4; ++mt) {
                short8 a = *(const short8*)(xk + (long)mt * 16 * Kd);
                acc[mt] = __builtin_amdgcn_mfma_f32_16x16x32_bf16(a, b, acc[mt], 0, 0, 0);
            }
        }
        __syncthreads();
    }

    // ---- epilogue: C/D row m = mt*16 + q*4 + r, col n = n0 + wv*16 + c ----
    const int nw = n0 + wv * 16 + c;
    #pragma unroll
    for (int mt = 0; mt < 4; ++mt)
        #pragma unroll
        for (int r = 0; r < 4; ++r)
            atomicAdd(&y[(long)(mt * 16 + q * 4 + r) * Nd + nw], acc[mt][r]);
}

// ---- fallback main (no ws): identical but inline f32->bf16 A loads ----
__global__ __launch_bounds__(256, 6)
void int4_main_nows_kernel(const float* __restrict__ xf,
                           const int*   __restrict__ wp,
                           const float* __restrict__ scales,
                           float*       __restrict__ y)
{
    __shared__ unsigned lds_w[64 * LDS_STRIDE];
    const int t = threadIdx.x, lane = t & 63, wv = t >> 6;
    const int q = lane >> 4, c = lane & 15;
    const int n0 = blockIdx.x * 64, kz = blockIdx.y;
    const int sr = t >> 4, ss = t & 15;
    const int*   wp_b = wp + (long)(kz * 1024 + sr) * Nd + n0 + 4 * ss;
    const float* sc_b = scales + (long)(kz * GPS) * Nd + n0 + 4 * ss;
    const float* xf_b = xf + (long)c * Kd + kz * 2048 + q * 8;
    float4v acc[4] = {};

    for (int g = 0; g < GPS; ++g) {
        const float4v s4 = *(const float4v*)(sc_b + (long)g * Nd);
        const int* wg = wp_b + (long)g * 64 * Nd;
        #pragma unroll
        for (int i = 0; i < 4; ++i) {
            int4v v = *(const int4v*)(wg + (long)i * 16 * Nd);
            uint4v pk;
            #pragma unroll
            for (int j = 0; j < 4; ++j) {
                float lo = (float)((v[j] & 15) - 8) * s4[j];
                float hi = (float)(((v[j] >> 4) & 15) - 8) * s4[j];
                pk[j] = f32_to_bf16_rn(lo) | (f32_to_bf16_rn(hi) << 16);
            }
            *(uint4v*)&lds_w[(i * 16 + sr) * LDS_STRIDE + 4 * ss] = pk;
        }
        __syncthreads();
        const float* xg = xf_b + g * 128;
        #pragma unroll
        for (int it = 0; it < 4; ++it) {
            union { short8 h; unsigned u[4]; } bu;
            #pragma unroll
            for (int i = 0; i < 4; ++i)
                bu.u[i] = lds_w[(it * 16 + q * 4 + i) * LDS_STRIDE + wv * 16 + c];
            const short8 b = bu.h;
            const float* xk = xg + it * 32;
            #pragma unroll
            for (int mt = 0; mt < 4; ++mt) {
                float4v a0 = *(const float4v*)(xk + (long)mt * 16 * Kd);
                float4v a1 = *(const float4v*)(xk + (long)mt * 16 * Kd + 4);
                union { unsigned short s[8]; short8 v; } r;
                #pragma unroll
                for (int j = 0; j < 4; ++j) {
                    r.s[j]     = (unsigned short)f32_to_bf16_rn(a0[j]);
                    r.s[4 + j] = (unsigned short)f32_to_bf16_rn(a1[j]);
                }
                acc[mt] = __builtin_amdgcn_mfma_f32_16x16x32_bf16(r.v, b, acc[mt], 0, 0, 0);
            }
        }
        __syncthreads();
    }
    const int nw = n0 + wv * 16 + c;
    #pragma unroll
    for (int mt = 0; mt < 4; ++mt)
        #pragma unroll
        for (int r = 0; r < 4; ++r)
            atomicAdd(&y[(long)(mt * 16 + q * 4 + r) * Nd + nw], acc[mt][r]);
}

extern "C" void kernel_launch(void* const* d_in, const int* in_sizes, int n_in,
                              void* d_out, int out_size, void* d_ws, size_t ws_size,
                              hipStream_t stream) {
    const float* x      = (const float*)d_in[0];
    const int*   wp     = (const int*)d_in[1];
    const float* scales = (const float*)d_in[2];
    const float* bias   = (const float*)d_in[3];
    float*       y      = (float*)d_out;

    init_y_kernel<<<dim3(1792), dim3(256), 0, stream>>>(bias, y);

    const size_t xb_bytes = (size_t)64 * Kd * sizeof(unsigned short); // 1 MB
    dim3 grid(Nd / 64, KSPLIT);   // (448, 4) -> 1792 blocks, 7 blocks/CU
    dim3 block(256);

    if (ws_size >= xb_bytes) {
        unsigned short* xb = (unsigned short*)d_ws;
        cvt_x_kernel<<<dim3(256), dim3(256), 0, stream>>>(x, xb);
        int4_main_kernel<<<grid, block, 0, stream>>>(xb, wp, scales, y);
    } else {
        int4_main_nows_kernel<<<grid, block, 0, stream>>>(x, wp, scales, y);
    }
}

// Round 5
// 755.137 us; speedup vs baseline: 1.0527x; 1.0167x over previous
//
#include <hip/hip_runtime.h>

// INT4PackedLinear: y[64,28672] = x[64,8192] @ dequant(w_packed, scales) + bias
// Dtype contract (verified R0-R3): x/scales/bias/y are FLOAT32, w_packed int32.
//
// R4 post-mortem: __syncthreads() emits s_waitcnt vmcnt(0) before s_barrier ->
// every group serialized a full HBM round trip (311us, 0.9 TB/s, both pipes idle).
// R5: true pipeline:
//  - LDS double-buffer, ONE lgkmcnt-only barrier per group (no vmcnt drain).
//  - w(g+1) register-prefetched one group ahead; dequant of w(g) is the only
//    vmcnt wait point and it retires only w(g) (oldest in FIFO).
//  - A-loads issued BEFORE w(g+1) each iter so A-waits never drain the HBM
//    prefetch (vmcnt retires in issue order).
//  - launch_bounds(256,4): <=128 VGPR, 16 waves/CU; LDS 34.8KB -> 4 blocks/CU.

typedef short  short8  __attribute__((ext_vector_type(8)));
typedef float  float4v __attribute__((ext_vector_type(4)));
typedef int    int4v   __attribute__((ext_vector_type(4)));
typedef unsigned int uint4v __attribute__((ext_vector_type(4)));

constexpr int Kd = 8192;
constexpr int Nd = 28672;
constexpr int KSPLIT = 4;           // 4 k-partitions of 2048
constexpr int GPS = 16;             // 128-k groups per partition
constexpr int LDS_STRIDE = 68;      // dwords/row: %4==0 (b128 align), 2-way reads (free)

__device__ __forceinline__ unsigned f32_to_bf16_rn(float f) {
    unsigned u = __builtin_bit_cast(unsigned, f);
    return (u + 0x7FFFu + ((u >> 16) & 1u)) >> 16;
}

// CK-style block barrier: waits LDS ops only; global loads stay in flight.
__device__ __forceinline__ void sync_lds() {
    asm volatile("s_waitcnt lgkmcnt(0)\n\ts_barrier" ::: "memory");
}

// ---- y := bias broadcast over 64 rows ----
__global__ __launch_bounds__(256)
void init_y_kernel(const float* __restrict__ bias, float* __restrict__ y) {
    const int gid = blockIdx.x * 256 + threadIdx.x;       // 458752 = 64*7168
    const int m  = gid / (Nd / 4);
    const int nq = gid % (Nd / 4);
    ((float4v*)y)[(long)m * (Nd / 4) + nq] = ((const float4v*)bias)[nq];
}

// ---- x f32 -> bf16 into workspace ----
__global__ __launch_bounds__(256)
void cvt_x_kernel(const float* __restrict__ x, unsigned short* __restrict__ o) {
    const int i = (blockIdx.x * 256 + threadIdx.x) * 8;
    float4v a = *(const float4v*)(x + i);
    float4v b = *(const float4v*)(x + i + 4);
    union { unsigned short s[8]; short8 v; } r;
    #pragma unroll
    for (int j = 0; j < 4; ++j) {
        r.s[j]     = (unsigned short)f32_to_bf16_rn(a[j]);
        r.s[4 + j] = (unsigned short)f32_to_bf16_rn(b[j]);
    }
    *(short8*)(o + i) = r.v;
}

// ---- main: grid (448, 4), block 256 ----
__global__ __launch_bounds__(256, 4)
void int4_main_kernel(const unsigned short* __restrict__ xb,
                      const int*            __restrict__ wp,
                      const float*          __restrict__ scales,
                      float*                __restrict__ y)
{
    __shared__ unsigned lds_w[2 * 64 * LDS_STRIDE];   // 34,816 B double buffer

    const int t    = threadIdx.x;
    const int lane = t & 63;
    const int wv   = t >> 6;            // wave 0..3 -> n-tile
    const int q    = lane >> 4;
    const int c    = lane & 15;
    const int n0   = blockIdx.x * 64;
    const int kz   = blockIdx.y;

    // staging role: row-in-band sr (0..15), 16B segment ss (0..15)
    const int sr = t >> 4, ss = t & 15;
    const int*   wp_b = wp + (long)(kz * 1024 + sr) * Nd + n0 + 4 * ss;
    const float* sc_b = scales + (long)(kz * GPS) * Nd + n0 + 4 * ss;
    const unsigned short* xb_b = xb + (long)c * Kd + kz * 2048 + q * 8;

    float4v acc[4] = {};
    int4v wc[4], wn[4];
    float4v scur, snxt;

    // prologue: group 0 w + scales in flight
    #pragma unroll
    for (int i = 0; i < 4; ++i)
        wc[i] = *(const int4v*)(wp_b + (long)i * 16 * Nd);
    scur = *(const float4v*)(sc_b);

    for (int g = 0; g < GPS; ++g) {
        unsigned* buf = &lds_w[(g & 1) * (64 * LDS_STRIDE)];

        // --- (1) A-loads for group g: issued FIRST (oldest -> never block on w) ---
        const unsigned short* xg = xb_b + g * 128;
        short8 areg[16];
        #pragma unroll
        for (int it = 0; it < 4; ++it)
            #pragma unroll
            for (int mt = 0; mt < 4; ++mt)
                areg[it * 4 + mt] = *(const short8*)(xg + it * 32 + (long)mt * 16 * Kd);

        // --- (2) prefetch w(g+1) + scales(g+1): in flight through barrier+compute ---
        if (g + 1 < GPS) {
            const int* wg = wp_b + (long)(g + 1) * 64 * Nd;
            #pragma unroll
            for (int i = 0; i < 4; ++i)
                wn[i] = *(const int4v*)(wg + (long)i * 16 * Nd);
            snxt = *(const float4v*)(sc_b + (long)(g + 1) * Nd);
        }

        // --- (3) dequant w(g) -> LDS; the only vmcnt wait, retires only w(g) ---
        #pragma unroll
        for (int i = 0; i < 4; ++i) {
            uint4v pk;
            #pragma unroll
            for (int j = 0; j < 4; ++j) {
                float lo = (float)((wc[i][j] & 15) - 8) * scur[j];
                float hi = (float)(((wc[i][j] >> 4) & 15) - 8) * scur[j];
                pk[j] = f32_to_bf16_rn(lo) | (f32_to_bf16_rn(hi) << 16);
            }
            *(uint4v*)&buf[(i * 16 + sr) * LDS_STRIDE + 4 * ss] = pk;
        }

        sync_lds();   // lgkmcnt(0) + s_barrier -- w(g+1)/A stay in flight

        // --- (4) compute: ds_read b-frags + MFMA (A already in regs) ---
        #pragma unroll
        for (int it = 0; it < 4; ++it) {
            union { short8 h; unsigned u[4]; } bu;
            #pragma unroll
            for (int i = 0; i < 4; ++i)
                bu.u[i] = buf[(it * 16 + q * 4 + i) * LDS_STRIDE + wv * 16 + c];
            const short8 b = bu.h;
            #pragma unroll
            for (int mt = 0; mt < 4; ++mt)
                acc[mt] = __builtin_amdgcn_mfma_f32_16x16x32_bf16(
                              areg[it * 4 + mt], b, acc[mt], 0, 0, 0);
        }

        // roll double-buffered registers
        #pragma unroll
        for (int i = 0; i < 4; ++i) wc[i] = wn[i];
        scur = snxt;
    }

    // ---- epilogue: C/D row m = mt*16 + q*4 + r, col n = n0 + wv*16 + c ----
    const int nw = n0 + wv * 16 + c;
    #pragma unroll
    for (int mt = 0; mt < 4; ++mt)
        #pragma unroll
        for (int r = 0; r < 4; ++r)
            atomicAdd(&y[(long)(mt * 16 + q * 4 + r) * Nd + nw], acc[mt][r]);
}

// ---- fallback main (no ws): R4 structure, inline f32->bf16 A loads ----
__global__ __launch_bounds__(256, 6)
void int4_main_nows_kernel(const float* __restrict__ xf,
                           const int*   __restrict__ wp,
                           const float* __restrict__ scales,
                           float*       __restrict__ y)
{
    __shared__ unsigned lds_w[64 * LDS_STRIDE];
    const int t = threadIdx.x, lane = t & 63, wv = t >> 6;
    const int q = lane >> 4, c = lane & 15;
    const int n0 = blockIdx.x * 64, kz = blockIdx.y;
    const int sr = t >> 4, ss = t & 15;
    const int*   wp_b = wp + (long)(kz * 1024 + sr) * Nd + n0 + 4 * ss;
    const float* sc_b = scales + (long)(kz * GPS) * Nd + n0 + 4 * ss;
    const float* xf_b = xf + (long)c * Kd + kz * 2048 + q * 8;
    float4v acc[4] = {};

    for (int g = 0; g < GPS; ++g) {
        const float4v s4 = *(const float4v*)(sc_b + (long)g * Nd);
        const int* wg = wp_b + (long)g * 64 * Nd;
        #pragma unroll
        for (int i = 0; i < 4; ++i) {
            int4v v = *(const int4v*)(wg + (long)i * 16 * Nd);
            uint4v pk;
            #pragma unroll
            for (int j = 0; j < 4; ++j) {
                float lo = (float)((v[j] & 15) - 8) * s4[j];
                float hi = (float)(((v[j] >> 4) & 15) - 8) * s4[j];
                pk[j] = f32_to_bf16_rn(lo) | (f32_to_bf16_rn(hi) << 16);
            }
            *(uint4v*)&lds_w[(i * 16 + sr) * LDS_STRIDE + 4 * ss] = pk;
        }
        __syncthreads();
        const float* xg = xf_b + g * 128;
        #pragma unroll
        for (int it = 0; it < 4; ++it) {
            union { short8 h; unsigned u[4]; } bu;
            #pragma unroll
            for (int i = 0; i < 4; ++i)
                bu.u[i] = lds_w[(it * 16 + q * 4 + i) * LDS_STRIDE + wv * 16 + c];
            const short8 b = bu.h;
            const float* xk = xg + it * 32;
            #pragma unroll
            for (int mt = 0; mt < 4; ++mt) {
                float4v a0 = *(const float4v*)(xk + (long)mt * 16 * Kd);
                float4v a1 = *(const float4v*)(xk + (long)mt * 16 * Kd + 4);
                union { unsigned short s[8]; short8 v; } r;
                #pragma unroll
                for (int j = 0; j < 4; ++j) {
                    r.s[j]     = (unsigned short)f32_to_bf16_rn(a0[j]);
                    r.s[4 + j] = (unsigned short)f32_to_bf16_rn(a1[j]);
                }
                acc[mt] = __builtin_amdgcn_mfma_f32_16x16x32_bf16(r.v, b, acc[mt], 0, 0, 0);
            }
        }
        __syncthreads();
    }
    const int nw = n0 + wv * 16 + c;
    #pragma unroll
    for (int mt = 0; mt < 4; ++mt)
        #pragma unroll
        for (int r = 0; r < 4; ++r)
            atomicAdd(&y[(long)(mt * 16 + q * 4 + r) * Nd + nw], acc[mt][r]);
}

extern "C" void kernel_launch(void* const* d_in, const int* in_sizes, int n_in,
                              void* d_out, int out_size, void* d_ws, size_t ws_size,
                              hipStream_t stream) {
    const float* x      = (const float*)d_in[0];
    const int*   wp     = (const int*)d_in[1];
    const float* scales = (const float*)d_in[2];
    const float* bias   = (const float*)d_in[3];
    float*       y      = (float*)d_out;

    init_y_kernel<<<dim3(1792), dim3(256), 0, stream>>>(bias, y);

    const size_t xb_bytes = (size_t)64 * Kd * sizeof(unsigned short); // 1 MB
    dim3 grid(Nd / 64, KSPLIT);   // (448, 4) -> 1792 blocks
    dim3 block(256);

    if (ws_size >= xb_bytes) {
        unsigned short* xb = (unsigned short*)d_ws;
        cvt_x_kernel<<<dim3(256), dim3(256), 0, stream>>>(x, xb);
        int4_main_kernel<<<grid, block, 0, stream>>>(xb, wp, scales, y);
    } else {
        int4_main_nows_kernel<<<grid, block, 0, stream>>>(x, wp, scales, y);
    }
}

// Round 6
// 720.501 us; speedup vs baseline: 1.1033x; 1.0481x over previous
//
#include <hip/hip_runtime.h>

// INT4PackedLinear: y[64,28672] = x[64,8192] @ dequant(w_packed, scales) + bias
// Dtype contract (verified R0-R5): x/scales/bias/y are FLOAT32, w_packed int32.
//
// R5 post-mortem: VGPR=64 proves the allocator sank my register prefetch; with
// in-order vmcnt every sunk wait drains the pipeline (293us, 1.06 TB/s).
// R6: global_load_lds (no dest VGPR -> unsinkable), LDS double-buffer, raw asm
// barriers (vmcnt(4) mid-iter keeps next group's DMA in flight; lgkmcnt-only
// post-compute), dequant-on-read (fma form, bit-identical), atomic epilogue.

typedef short  short8  __attribute__((ext_vector_type(8)));
typedef float  float4v __attribute__((ext_vector_type(4)));
typedef int    int4v   __attribute__((ext_vector_type(4)));
typedef unsigned int uint4v __attribute__((ext_vector_type(4)));

constexpr int Kd = 8192;
constexpr int Nd = 28672;
constexpr int KSPLIT = 4;           // 4 k-partitions of 2048
constexpr int GPS = 16;             // 128-k groups per partition

__device__ __forceinline__ unsigned f32_to_bf16_rn(float f) {
    unsigned u = __builtin_bit_cast(unsigned, f);
    return (u + 0x7FFFu + ((u >> 16) & 1u)) >> 16;
}

// async global->LDS DMA, 16B per lane; LDS dst = wave-uniform base + lane*16.
__device__ __forceinline__ void async_copy16(const int* g, unsigned* l) {
    __builtin_amdgcn_global_load_lds(
        (const __attribute__((address_space(1))) unsigned int*)g,
        (__attribute__((address_space(3))) unsigned int*)l,
        16, 0, 0);
}

// ---- y := bias broadcast over 64 rows ----
__global__ __launch_bounds__(256)
void init_y_kernel(const float* __restrict__ bias, float* __restrict__ y) {
    const int gid = blockIdx.x * 256 + threadIdx.x;       // 458752 = 64*7168
    const int m  = gid / (Nd / 4);
    const int nq = gid % (Nd / 4);
    ((float4v*)y)[(long)m * (Nd / 4) + nq] = ((const float4v*)bias)[nq];
}

// ---- x f32 -> bf16 into workspace ----
__global__ __launch_bounds__(256)
void cvt_x_kernel(const float* __restrict__ x, unsigned short* __restrict__ o) {
    const int i = (blockIdx.x * 256 + threadIdx.x) * 8;
    float4v a = *(const float4v*)(x + i);
    float4v b = *(const float4v*)(x + i + 4);
    union { unsigned short s[8]; short8 v; } r;
    #pragma unroll
    for (int j = 0; j < 4; ++j) {
        r.s[j]     = (unsigned short)f32_to_bf16_rn(a[j]);
        r.s[4 + j] = (unsigned short)f32_to_bf16_rn(b[j]);
    }
    *(short8*)(o + i) = r.v;
}

// ---- main: grid (448, 4), block 256 ----
__global__ __launch_bounds__(256, 4)
void int4_main_kernel(const unsigned short* __restrict__ xb,
                      const int*            __restrict__ wp,
                      const float*          __restrict__ scales,
                      float*                __restrict__ y)
{
    __shared__ unsigned lds_w[2 * 4096];   // 2 x 16KB raw w dwords, [64 rows][64 n]

    const int t    = threadIdx.x;
    const int lane = t & 63;
    const int wv   = t >> 6;            // wave 0..3 -> n-tile AND staging row-band
    const int q    = lane >> 4;
    const int c    = lane & 15;
    const int n0   = blockIdx.x * 64;
    const int kz   = blockIdx.y;

    // staging: wave wv covers rows [wv*16, wv*16+16); instr i covers 4 rows.
    // lane: row += (lane>>4), 16B col segment = lane&15. LDS layout matches
    // DMA's (base + lane*16B): row-major, 256B per row.
    const int* wbase = wp + (long)(kz * 1024 + wv * 16 + (lane >> 4)) * Nd
                          + n0 + 4 * (lane & 15);
    const int lbase = wv * 16 * 64;     // dwords within a buffer

    const unsigned short* xb_b = xb + (long)c * Kd + kz * 2048 + q * 8;
    const float* sc_b = scales + (long)(kz * GPS) * Nd + n0 + wv * 16 + c;

    float4v acc[4] = {};

    // prologue: stage group 0 into buffer 0
    #pragma unroll
    for (int i = 0; i < 4; ++i)
        async_copy16(wbase + (long)i * 4 * Nd, &lds_w[lbase + i * 256]);

    for (int g = 0; g < GPS; ++g) {
        // --- A-frags + scale for g (L2-resident), issued before next staging ---
        short8 areg[16];
        const unsigned short* xg = xb_b + g * 128;
        #pragma unroll
        for (int it = 0; it < 4; ++it)
            #pragma unroll
            for (int mt = 0; mt < 4; ++mt)
                areg[it * 4 + mt] = *(const short8*)(xg + it * 32 + (long)mt * 16 * Kd);
        const float s   = sc_b[(long)g * Nd];
        const float m8s = -8.0f * s;

        // --- stage group g+1 into the other buffer (stays in flight) ---
        if (g + 1 < GPS) {
            const int* wg = wbase + (long)(g + 1) * 64 * Nd;
            unsigned* lb = &lds_w[((g + 1) & 1) * 4096 + lbase];
            #pragma unroll
            for (int i = 0; i < 4; ++i)
                async_copy16(wg + (long)i * 4 * Nd, lb + i * 256);
        }

        // --- wait: staging(g) landed (>=4 newer vm-ops exist in all iters;
        //     in-order retirement => vmcnt(4) guarantees g retired). ---
        asm volatile("s_waitcnt vmcnt(4)\n\ts_barrier" ::: "memory");

        // --- compute g: ds_read raw w, dequant (exact), MFMA ---
        const unsigned* buf = &lds_w[(g & 1) * 4096];
        #pragma unroll
        for (int it = 0; it < 4; ++it) {
            union { short8 h; unsigned u[4]; } bu;
            #pragma unroll
            for (int i = 0; i < 4; ++i) {
                unsigned v = buf[(it * 16 + q * 4 + i) * 64 + wv * 16 + c];
                float lo = fmaf((float)(v & 15u), s, m8s);          // ==((v&15)-8)*s
                float hi = fmaf((float)((v >> 4) & 15u), s, m8s);
                bu.u[i] = f32_to_bf16_rn(lo) | (f32_to_bf16_rn(hi) << 16);
            }
            #pragma unroll
            for (int mt = 0; mt < 4; ++mt)
                acc[mt] = __builtin_amdgcn_mfma_f32_16x16x32_bf16(
                              areg[it * 4 + mt], bu.h, acc[mt], 0, 0, 0);
        }

        // --- all waves done reading before next DMA overwrites this buffer ---
        asm volatile("s_waitcnt lgkmcnt(0)\n\ts_barrier" ::: "memory");
    }

    // ---- epilogue: C/D row m = mt*16 + q*4 + r, col n = n0 + wv*16 + c ----
    const int nw = n0 + wv * 16 + c;
    #pragma unroll
    for (int mt = 0; mt < 4; ++mt)
        #pragma unroll
        for (int r = 0; r < 4; ++r)
            atomicAdd(&y[(long)(mt * 16 + q * 4 + r) * Nd + nw], acc[mt][r]);
}

// ---- fallback main (no ws): R4 structure, inline f32->bf16 A loads ----
__global__ __launch_bounds__(256, 6)
void int4_main_nows_kernel(const float* __restrict__ xf,
                           const int*   __restrict__ wp,
                           const float* __restrict__ scales,
                           float*       __restrict__ y)
{
    constexpr int LDS_STRIDE = 68;
    __shared__ unsigned lds_w[64 * LDS_STRIDE];
    const int t = threadIdx.x, lane = t & 63, wv = t >> 6;
    const int q = lane >> 4, c = lane & 15;
    const int n0 = blockIdx.x * 64, kz = blockIdx.y;
    const int sr = t >> 4, ss = t & 15;
    const int*   wp_b = wp + (long)(kz * 1024 + sr) * Nd + n0 + 4 * ss;
    const float* sc_b = scales + (long)(kz * GPS) * Nd + n0 + 4 * ss;
    const float* xf_b = xf + (long)c * Kd + kz * 2048 + q * 8;
    float4v acc[4] = {};

    for (int g = 0; g < GPS; ++g) {
        const float4v s4 = *(const float4v*)(sc_b + (long)g * Nd);
        const int* wg = wp_b + (long)g * 64 * Nd;
        #pragma unroll
        for (int i = 0; i < 4; ++i) {
            int4v v = *(const int4v*)(wg + (long)i * 16 * Nd);
            uint4v pk;
            #pragma unroll
            for (int j = 0; j < 4; ++j) {
                float lo = (float)((v[j] & 15) - 8) * s4[j];
                float hi = (float)(((v[j] >> 4) & 15) - 8) * s4[j];
                pk[j] = f32_to_bf16_rn(lo) | (f32_to_bf16_rn(hi) << 16);
            }
            *(uint4v*)&lds_w[(i * 16 + sr) * LDS_STRIDE + 4 * ss] = pk;
        }
        __syncthreads();
        const float* xg = xf_b + g * 128;
        #pragma unroll
        for (int it = 0; it < 4; ++it) {
            union { short8 h; unsigned u[4]; } bu;
            #pragma unroll
            for (int i = 0; i < 4; ++i)
                bu.u[i] = lds_w[(it * 16 + q * 4 + i) * LDS_STRIDE + wv * 16 + c];
            const short8 b = bu.h;
            const float* xk = xg + it * 32;
            #pragma unroll
            for (int mt = 0; mt < 4; ++mt) {
                float4v a0 = *(const float4v*)(xk + (long)mt * 16 * Kd);
                float4v a1 = *(const float4v*)(xk + (long)mt * 16 * Kd + 4);
                union { unsigned short s[8]; short8 v; } r;
                #pragma unroll
                for (int j = 0; j < 4; ++j) {
                    r.s[j]     = (unsigned short)f32_to_bf16_rn(a0[j]);
                    r.s[4 + j] = (unsigned short)f32_to_bf16_rn(a1[j]);
                }
                acc[mt] = __builtin_amdgcn_mfma_f32_16x16x32_bf16(r.v, b, acc[mt], 0, 0, 0);
            }
        }
        __syncthreads();
    }
    const int nw = n0 + wv * 16 + c;
    #pragma unroll
    for (int mt = 0; mt < 4; ++mt)
        #pragma unroll
        for (int r = 0; r < 4; ++r)
            atomicAdd(&y[(long)(mt * 16 + q * 4 + r) * Nd + nw], acc[mt][r]);
}

extern "C" void kernel_launch(void* const* d_in, const int* in_sizes, int n_in,
                              void* d_out, int out_size, void* d_ws, size_t ws_size,
                              hipStream_t stream) {
    const float* x      = (const float*)d_in[0];
    const int*   wp     = (const int*)d_in[1];
    const float* scales = (const float*)d_in[2];
    const float* bias   = (const float*)d_in[3];
    float*       y      = (float*)d_out;

    init_y_kernel<<<dim3(1792), dim3(256), 0, stream>>>(bias, y);

    const size_t xb_bytes = (size_t)64 * Kd * sizeof(unsigned short); // 1 MB
    dim3 grid(Nd / 64, KSPLIT);   // (448, 4) -> 1792 blocks
    dim3 block(256);

    if (ws_size >= xb_bytes) {
        unsigned short* xb = (unsigned short*)d_ws;
        cvt_x_kernel<<<dim3(256), dim3(256), 0, stream>>>(x, xb);
        int4_main_kernel<<<grid, block, 0, stream>>>(xb, wp, scales, y);
    } else {
        int4_main_nows_kernel<<<grid, block, 0, stream>>>(x, wp, scales, y);
    }
}

// Round 7
// 630.694 us; speedup vs baseline: 1.2605x; 1.1424x over previous
//
#include <hip/hip_runtime.h>

// INT4PackedLinear: y[64,28672] = x[64,8192] @ dequant(w_packed, scales) + bias
// Dtype contract (verified R0-R6): x/scales/bias/y are FLOAT32, w_packed int32.
//
// R6 post-mortem: register A-loads inside the compute phase re-couple compute
// to the w-DMA stream via in-order vmcnt (compiler-inserted waits) -> ~260us.
// R7: compute phase has ZERO vmem. w, x, scales all staged via global_load_lds
// into four separate __shared__ objects (per-object alias analysis), 64-k
// half-group double buffer, explicit vmcnt(4)/vmcnt(0)+barrier asm, XOR-swizzled
// LDS layouts (w-reads 2-way free, A-reads b128 at the 8-clk floor) compatible
// with the DMA's fixed lane*16B placement. 4 blocks/CU (36KB LDS), grid (448,4).

typedef short  short8  __attribute__((ext_vector_type(8)));
typedef float  float4v __attribute__((ext_vector_type(4)));
typedef int    int4v   __attribute__((ext_vector_type(4)));
typedef unsigned int uint4v __attribute__((ext_vector_type(4)));

constexpr int Kd = 8192;
constexpr int Nd = 28672;
constexpr int KSPLIT = 4;           // 4 k-partitions of 2048

__device__ __forceinline__ unsigned f32_to_bf16_rn(float f) {
    unsigned u = __builtin_bit_cast(unsigned, f);
    return (u + 0x7FFFu + ((u >> 16) & 1u)) >> 16;
}

// async global->LDS DMA: 16B per lane at (wave-uniform base) + lane*16B.
__device__ __forceinline__ void async16(const void* g, void* l) {
    __builtin_amdgcn_global_load_lds(
        (const __attribute__((address_space(1))) unsigned*)g,
        (__attribute__((address_space(3))) unsigned*)l, 16, 0, 0);
}

// ---- y := bias broadcast over 64 rows ----
__global__ __launch_bounds__(256)
void init_y_kernel(const float* __restrict__ bias, float* __restrict__ y) {
    const int gid = blockIdx.x * 256 + threadIdx.x;       // 458752 = 64*7168
    const int m  = gid / (Nd / 4);
    const int nq = gid % (Nd / 4);
    ((float4v*)y)[(long)m * (Nd / 4) + nq] = ((const float4v*)bias)[nq];
}

// ---- x f32 -> bf16 into workspace ----
__global__ __launch_bounds__(256)
void cvt_x_kernel(const float* __restrict__ x, unsigned short* __restrict__ o) {
    const int i = (blockIdx.x * 256 + threadIdx.x) * 8;
    float4v a = *(const float4v*)(x + i);
    float4v b = *(const float4v*)(x + i + 4);
    union { unsigned short s[8]; short8 v; } r;
    #pragma unroll
    for (int j = 0; j < 4; ++j) {
        r.s[j]     = (unsigned short)f32_to_bf16_rn(a[j]);
        r.s[4 + j] = (unsigned short)f32_to_bf16_rn(b[j]);
    }
    *(short8*)(o + i) = r.v;
}

// ---- main: grid (448, 4), block 256 ----
__global__ __launch_bounds__(256, 4)
void int4_main_kernel(const unsigned short* __restrict__ xw,
                      const int*            __restrict__ wp,
                      const float*          __restrict__ scales,
                      float*                __restrict__ y)
{
    // Separate objects so the waitcnt pass can disambiguate DMA targets.
    __shared__ unsigned wb0[2048], wb1[2048];   // w half-group: 32 rows x 64 n
    __shared__ unsigned xb0[2048], xb1[2048];   // x half-group: 64 m x 8 chunks
    __shared__ unsigned sb[1024];               // scales: 16 groups x 64 n (f32)

    const int t = threadIdx.x, lane = t & 63, wv = t >> 6;
    const int q = lane >> 4, c = lane & 15;
    const int l4 = lane >> 4, l15 = lane & 15;
    const int n0 = blockIdx.x * 64, kz = blockIdx.y;

    // ---- per-lane DMA source pointers ----
    // w instr i: row = wv*8 + i*4 + l4 ; col = (l15*4) ^ (((wv*2+i)&3)<<4)
    const int* wsrc0; const int* wsrc1;
    {
        int r0 = wv * 8 + 0 * 4 + l4, c0 = (l15 * 4) ^ (((wv * 2 + 0) & 3) << 4);
        int r1 = wv * 8 + 1 * 4 + l4, c1 = (l15 * 4) ^ (((wv * 2 + 1) & 3) << 4);
        wsrc0 = wp + (long)(kz * 1024 + r0) * Nd + n0 + c0;
        wsrc1 = wp + (long)(kz * 1024 + r1) * Nd + n0 + c1;
    }
    // x instr i: s = wv*128 + i*64 + lane ; m = s>>3 ; kq = (s&7)^(m&7)
    const unsigned short* xsrc0; const unsigned short* xsrc1;
    {
        int s0 = wv * 128 + 0 * 64 + lane, m0 = s0 >> 3, k0 = (s0 & 7) ^ (m0 & 7);
        int s1 = wv * 128 + 1 * 64 + lane, m1 = s1 >> 3, k1 = (s1 & 7) ^ (m1 & 7);
        xsrc0 = xw + (long)m0 * Kd + kz * 2048 + k0 * 8;
        xsrc1 = xw + (long)m1 * Kd + kz * 2048 + k1 * 8;
    }
    const int ldof = wv * 512;   // dwords; instr1 adds +256

    // ---- prologue: scales (4KB, one DMA) + half-group 0 ----
    {
        const float* ssrc = scales + (long)(kz * 16 + (t >> 4)) * Nd + n0 + (t & 15) * 4;
        async16(ssrc, sb + wv * 256);
    }
    async16(wsrc0, wb0 + ldof);
    async16(wsrc1, wb0 + ldof + 256);
    async16(xsrc0, xb0 + ldof);
    async16(xsrc1, xb0 + ldof + 256);

    float4v acc[4] = {};

    auto stage = [&](int hg, unsigned* wbuf, unsigned* xbuf) {
        const long wof = (long)hg * 32 * Nd;    // 32 packed rows per half-group
        const long xof = (long)hg * 64;         // 64 k elems per half-group
        async16(wsrc0 + wof, wbuf + ldof);
        async16(wsrc1 + wof, wbuf + ldof + 256);
        async16(xsrc0 + xof, xbuf + ldof);
        async16(xsrc1 + xof, xbuf + ldof + 256);
    };

    auto compute = [&](const unsigned* wbuf, const unsigned* xbuf, int g) {
        const float s   = __builtin_bit_cast(float, sb[g * 64 + wv * 16 + c]);
        const float m8s = -8.0f * s;
        #pragma unroll
        for (int it = 0; it < 2; ++it) {
            union { short8 h; unsigned u[4]; } bu;
            #pragma unroll
            for (int i = 0; i < 4; ++i) {
                unsigned v = wbuf[(it * 16 + q * 4 + i) * 64 + ((wv * 16 + c) ^ (q << 4))];
                float lo = fmaf((float)(v & 15u), s, m8s);          // ==((v&15)-8)*s
                float hi = fmaf((float)((v >> 4) & 15u), s, m8s);
                bu.u[i] = f32_to_bf16_rn(lo) | (f32_to_bf16_rn(hi) << 16);
            }
            #pragma unroll
            for (int mt = 0; mt < 4; ++mt) {
                int m = mt * 16 + c;
                int slot = m * 8 + ((it * 4 + q) ^ (c & 7));        // XOR-swizzled
                short8 a = *(const short8*)(xbuf + slot * 4);
                acc[mt] = __builtin_amdgcn_mfma_f32_16x16x32_bf16(a, bu.h, acc[mt], 0, 0, 0);
            }
        }
    };

    for (int hgp = 0; hgp < 16; ++hgp) {
        const int hg = 2 * hgp;
        // even half-group: compute buf0(hg); stage hg+1 -> buf1
        stage(hg + 1, wb1, xb1);
        asm volatile("s_waitcnt vmcnt(4)\ns_barrier" ::: "memory");
        compute(wb0, xb0, hgp);
        asm volatile("s_waitcnt lgkmcnt(0)\ns_barrier" ::: "memory");
        // odd half-group: compute buf1(hg+1); stage hg+2 -> buf0
        if (hgp < 15) {
            stage(hg + 2, wb0, xb0);
            asm volatile("s_waitcnt vmcnt(4)\ns_barrier" ::: "memory");
        } else {
            asm volatile("s_waitcnt vmcnt(0)\ns_barrier" ::: "memory");
        }
        compute(wb1, xb1, hgp);
        asm volatile("s_waitcnt lgkmcnt(0)\ns_barrier" ::: "memory");
    }

    // ---- epilogue: C/D row m = mt*16 + q*4 + r, col n = n0 + wv*16 + c ----
    const int nw = n0 + wv * 16 + c;
    #pragma unroll
    for (int mt = 0; mt < 4; ++mt)
        #pragma unroll
        for (int r = 0; r < 4; ++r)
            atomicAdd(&y[(long)(mt * 16 + q * 4 + r) * Nd + nw], acc[mt][r]);
}

// ---- fallback main (no ws): R4 structure, inline f32->bf16 A loads ----
__global__ __launch_bounds__(256, 6)
void int4_main_nows_kernel(const float* __restrict__ xf,
                           const int*   __restrict__ wp,
                           const float* __restrict__ scales,
                           float*       __restrict__ y)
{
    constexpr int LDS_STRIDE = 68;
    __shared__ unsigned lds_w[64 * LDS_STRIDE];
    const int t = threadIdx.x, lane = t & 63, wv = t >> 6;
    const int q = lane >> 4, c = lane & 15;
    const int n0 = blockIdx.x * 64, kz = blockIdx.y;
    const int sr = t >> 4, ss = t & 15;
    const int*   wp_b = wp + (long)(kz * 1024 + sr) * Nd + n0 + 4 * ss;
    const float* sc_b = scales + (long)(kz * 16) * Nd + n0 + 4 * ss;
    const float* xf_b = xf + (long)c * Kd + kz * 2048 + q * 8;
    float4v acc[4] = {};

    for (int g = 0; g < 16; ++g) {
        const float4v s4 = *(const float4v*)(sc_b + (long)g * Nd);
        const int* wg = wp_b + (long)g * 64 * Nd;
        #pragma unroll
        for (int i = 0; i < 4; ++i) {
            int4v v = *(const int4v*)(wg + (long)i * 16 * Nd);
            uint4v pk;
            #pragma unroll
            for (int j = 0; j < 4; ++j) {
                float lo = (float)((v[j] & 15) - 8) * s4[j];
                float hi = (float)(((v[j] >> 4) & 15) - 8) * s4[j];
                pk[j] = f32_to_bf16_rn(lo) | (f32_to_bf16_rn(hi) << 16);
            }
            *(uint4v*)&lds_w[(i * 16 + sr) * LDS_STRIDE + 4 * ss] = pk;
        }
        __syncthreads();
        const float* xg = xf_b + g * 128;
        #pragma unroll
        for (int it = 0; it < 4; ++it) {
            union { short8 h; unsigned u[4]; } bu;
            #pragma unroll
            for (int i = 0; i < 4; ++i)
                bu.u[i] = lds_w[(it * 16 + q * 4 + i) * LDS_STRIDE + wv * 16 + c];
            const short8 b = bu.h;
            const float* xk = xg + it * 32;
            #pragma unroll
            for (int mt = 0; mt < 4; ++mt) {
                float4v a0 = *(const float4v*)(xk + (long)mt * 16 * Kd);
                float4v a1 = *(const float4v*)(xk + (long)mt * 16 * Kd + 4);
                union { unsigned short s[8]; short8 v; } r;
                #pragma unroll
                for (int j = 0; j < 4; ++j) {
                    r.s[j]     = (unsigned short)f32_to_bf16_rn(a0[j]);
                    r.s[4 + j] = (unsigned short)f32_to_bf16_rn(a1[j]);
                }
                acc[mt] = __builtin_amdgcn_mfma_f32_16x16x32_bf16(r.v, b, acc[mt], 0, 0, 0);
            }
        }
        __syncthreads();
    }
    const int nw = n0 + wv * 16 + c;
    #pragma unroll
    for (int mt = 0; mt < 4; ++mt)
        #pragma unroll
        for (int r = 0; r < 4; ++r)
            atomicAdd(&y[(long)(mt * 16 + q * 4 + r) * Nd + nw], acc[mt][r]);
}

extern "C" void kernel_launch(void* const* d_in, const int* in_sizes, int n_in,
                              void* d_out, int out_size, void* d_ws, size_t ws_size,
                              hipStream_t stream) {
    const float* x      = (const float*)d_in[0];
    const int*   wp     = (const int*)d_in[1];
    const float* scales = (const float*)d_in[2];
    const float* bias   = (const float*)d_in[3];
    float*       y      = (float*)d_out;

    init_y_kernel<<<dim3(1792), dim3(256), 0, stream>>>(bias, y);

    const size_t xb_bytes = (size_t)64 * Kd * sizeof(unsigned short); // 1 MB
    dim3 grid(Nd / 64, KSPLIT);   // (448, 4) -> 1792 blocks, 4 resident/CU
    dim3 block(256);

    if (ws_size >= xb_bytes) {
        unsigned short* xb = (unsigned short*)d_ws;
        cvt_x_kernel<<<dim3(256), dim3(256), 0, stream>>>(x, xb);
        int4_main_kernel<<<grid, block, 0, stream>>>(xb, wp, scales, y);
    } else {
        int4_main_nows_kernel<<<grid, block, 0, stream>>>(x, wp, scales, y);
    }
}